// Round 9
// baseline (53.375 us; speedup 1.0000x reference)
//
#include <hip/hip_runtime.h>

// N=8, C=256, H=W=64, A=9, bs=8, F=8, K=64, M=A*N*K=4608
constexpr int N_ = 8, C_ = 256, H_ = 64, W_ = 64, A_ = 9, F_ = 8, K_ = 64;
constexpr int M_ = A_ * N_ * K_;
constexpr int NPOS = 512;                  // N*F*F positions
constexpr int PSTRIDE = 9 * 32;            // per-position partials: [9 anchors][32 slices]
constexpr int NJOBS2 = A_ * N_ * (C_ / 8); // 2304 fused-rois jobs (8 ch each)
#define ALPHA_BS 0.8f                      // ALPHA(0.1) * bs(8)
#define L2E 1.442695040888963f

typedef float f32x2 __attribute__((ext_vector_type(2)));

// ---------------------------------------------------------------------------
// kA: conv partials, W register-stationary. 2048 blocks = (pair, g, chunk):
// chunk = bi&7 == XCD id; g = (n,gy); pair picks 2 of 8 gx. Thread t =
// (cl=t>>3, r=t&7) holds W[a][c][r][0..7] in regs (18 float4). Per gx:
// 2 feat float4 loads, 72 FMA, then FULL 6-step butterfly (rows + the wave's
// 8 channels) -> one scalar per (wave, a, gx) -> partials[p][a][chunk*4+wid].
// Partials shrink 4.7MB -> 589KB vs per-channel layout.
// ---------------------------------------------------------------------------
__global__ __launch_bounds__(256) void kA(const float* __restrict__ feat,
                                          const float* __restrict__ Wreg,
                                          float* __restrict__ partials) {
    const int bi = blockIdx.x;
    const int chunk = bi & 7;
    const int g = (bi >> 3) & 63;
    const int pair = bi >> 9;              // 0..3
    const int n = g >> 3, gy = g & 7;
    const int t = threadIdx.x;
    const int lane = t & 63, wid = t >> 6;
    const int r = t & 7;
    const int c = chunk * 32 + (t >> 3);

    const float* wp = Wreg + chunk * 2048 + t * 8;
    float4 w0[9], w1[9];
#pragma unroll
    for (int a = 0; a < 9; ++a) {
        w0[a] = *(const float4*)(wp + (size_t)a * 16384);
        w1[a] = *(const float4*)(wp + (size_t)a * 16384 + 4);
    }
    const float* frow = feat + (((size_t)n * C_ + c) * H_ + gy * 8 + r) * W_;
#pragma unroll
    for (int i = 0; i < 2; ++i) {
        const int gx = pair * 2 + i;
        const float4 f0 = *(const float4*)(frow + gx * 8);
        const float4 f1 = *(const float4*)(frow + gx * 8 + 4);
        float* pp = partials + (size_t)(g * 8 + gx) * PSTRIDE + chunk * 4 + wid;
#pragma unroll
        for (int a = 0; a < 9; ++a) {
            float s = f0.x * w0[a].x + f0.y * w0[a].y + f0.z * w0[a].z + f0.w * w0[a].w;
            s = fmaf(f1.x, w1[a].x, s);
            s = fmaf(f1.y, w1[a].y, s);
            s = fmaf(f1.z, w1[a].z, s);
            s = fmaf(f1.w, w1[a].w, s);
            s += __shfl_xor(s, 1, 64);     // rows (lane bits 0..2)
            s += __shfl_xor(s, 2, 64);
            s += __shfl_xor(s, 4, 64);
            s += __shfl_xor(s, 8, 64);     // the wave's 8 channels (bits 3..5)
            s += __shfl_xor(s, 16, 64);
            s += __shfl_xor(s, 32, 64);
            if (lane == 0) pp[a * 32] = s;
        }
    }
}

// ---------------------------------------------------------------------------
// kB: finish conv (72 threads: float4 + 3 shfl) + tanh offsets + bilinear
// sample, channel-split. 1024 blocks = (position, c-half): tile[128][65] =
// 33.3KB -> 4 blocks/CU. Offsets bounded by +-0.8 => corners in-block.
// ---------------------------------------------------------------------------
__global__ __launch_bounds__(256, 4) void kB(const float* __restrict__ feat,
                                             const float* __restrict__ partials,
                                             const float* __restrict__ breg,
                                             float* __restrict__ rfb) {
    __shared__ float tile[128][65];
    __shared__ float sW[9][4];
    __shared__ int   sI[9][4];

    const int bi = blockIdx.x;
    const int u  = (bi & 7) * 128 + (bi >> 3);  // XCD x -> image n = x
    const int b = u >> 1, half = u & 1;
    const int n = b >> 6, gy = (b >> 3) & 7, gx = b & 7;
    const int t = threadIdx.x;

    if (t < 72) {
        const int a = t >> 3, q = t & 7;
        const float4 v = *(const float4*)(partials + (size_t)b * PSTRIDE + a * 32 + q * 4);
        float s = v.x + v.y + v.z + v.w;
        s += __shfl_xor(s, 1, 64);         // sum the 8 q-slices
        s += __shfl_xor(s, 2, 64);
        s += __shfl_xor(s, 4, 64);
        if (q == 0) {
            float rr  = s + breg[a];
            float off = ALPHA_BS * tanhf(rr);
            float cx = 3.5f + 8.0f * gx + off;
            float cy = 3.5f + 8.0f * gy + off;
            float x0f = floorf(cx), y0f = floorf(cy);
            float wx = cx - x0f, wy = cy - y0f;
            int x0 = min(max((int)x0f, 0), W_ - 1);
            int x1 = min(x0 + 1, W_ - 1);
            int y0 = min(max((int)y0f, 0), H_ - 1);
            int y1 = min(y0 + 1, H_ - 1);
            int lx0 = x0 - gx * 8, lx1 = x1 - gx * 8;
            int ly0 = y0 - gy * 8, ly1 = y1 - gy * 8;
            sI[a][0] = ly0 * 8 + lx0;
            sI[a][1] = ly0 * 8 + lx1;
            sI[a][2] = ly1 * 8 + lx0;
            sI[a][3] = ly1 * 8 + lx1;
            sW[a][0] = (1.f - wx) * (1.f - wy);
            sW[a][1] = wx * (1.f - wy);
            sW[a][2] = (1.f - wx) * wy;
            sW[a][3] = wx * wy;
        }
    }

    const float* fb = feat + (((size_t)n * C_ + half * 128) * H_ + gy * 8) * W_ + gx * 8;
#pragma unroll
    for (int it = 0; it < 8; ++it) {
        int q = t + 256 * it;
        int c = q >> 4, rr = (q >> 1) & 7, h = q & 1;
        float4 v = *(const float4*)(fb + ((size_t)c * H_ + rr) * W_ + h * 4);
        int e = rr * 8 + h * 4;
        tile[c][e + 0] = v.x;
        tile[c][e + 1] = v.y;
        tile[c][e + 2] = v.z;
        tile[c][e + 3] = v.w;
    }
    __syncthreads();

    const int kidx = gy * 8 + gx;
    const int cl = t & 127;
    const int p = t >> 7;                  // wave-pair: anchors 0-4 / 5-8
    for (int a = p ? 5 : 0; a < (p ? 9 : 5); ++a) {
        float v = sW[a][0] * tile[cl][sI[a][0]] + sW[a][1] * tile[cl][sI[a][1]] +
                  sW[a][2] * tile[cl][sI[a][2]] + sW[a][3] * tile[cl][sI[a][3]];
        rfb[((size_t)(a * N_ + n) * K_ + kidx) * C_ + half * 128 + cl] = v;
    }
}

// ---------------------------------------------------------------------------
// kRf: both rois stages fused. 2304 blocks = (na, 8-ch chunk). Wave w owns
// channel PAIR cp=2w; lane = j. a_i broadcast = one uniform ds_read_b64 per
// i; f32x2 arithmetic -> v_pk_fma_f32. Stage-2's a = stage-1's o1 registers
// (LDS only for the i-broadcast). launch_bounds(256,4): VGPR<=128 — the
// (256,8) variant risked a silent spill at the 64-VGPR occupancy cliff.
// ---------------------------------------------------------------------------
__global__ __launch_bounds__(256, 4) void kRf(const float* __restrict__ rois_a,
                                              const float* __restrict__ rfb,
                                              const float* __restrict__ rois_c,
                                              float* __restrict__ out) {
    __shared__ __align__(16) float sa[64][10];
    __shared__ __align__(16) float sb[64][10];
    __shared__ __align__(16) float sc[64][10];

    const int bi = blockIdx.x;
    const int j  = (bi & 7) * 288 + (bi >> 3);  // XCD-chunked
    const int na = j >> 5;
    const int cb = (j & 31) * 8;
    const int t = threadIdx.x, lane = t & 63, w = t >> 6;
    const int cp = 2 * w;                       // this wave's channel pair
    const size_t base = (size_t)na * 64;

    float rc[2];
#pragma unroll
    for (int k = 0; k < 2; ++k) {
        int idx = t + 256 * k;
        int i = idx >> 3, cc = idx & 7;
        sa[i][cc] = rois_a[(base + i) * 256 + cb + cc];
        sb[i][cc] = rfb[(base + i) * 256 + cb + cc];
        rc[k]     = rois_c[(base + i) * 256 + cb + cc];
    }
    __syncthreads();

    // ---- stage 1: a = rois_a (sa), b = sampled (sb) ----
    const f32x2 a1 = *(const f32x2*)&sa[lane][cp];
    const f32x2 b1 = *(const f32x2*)&sb[lane][cp];
    f32x2 o1;
    {
        float mx0 = a1.x, mn0 = a1.x, mx1 = a1.y, mn1 = a1.y;
#pragma unroll
        for (int s = 32; s; s >>= 1) {
            mx0 = fmaxf(mx0, __shfl_xor(mx0, s, 64));
            mn0 = fminf(mn0, __shfl_xor(mn0, s, 64));
            mx1 = fmaxf(mx1, __shfl_xor(mx1, s, 64));
            mn1 = fminf(mn1, __shfl_xor(mn1, s, 64));
        }
        f32x2 m;
        m.x = b1.x > 0.f ? b1.x * mx0 : b1.x * mn0;
        m.y = b1.y > 0.f ? b1.y * mx1 : b1.y * mn1;
        const f32x2 bl2 = b1 * L2E;
        const f32x2 ml2 = -m * L2E;
        f32x2 den = {0.f, 0.f}, num = {0.f, 0.f};
#pragma unroll 16
        for (int i = 0; i < 64; ++i) {
            const f32x2 av = *(const f32x2*)&sa[i][cp];   // uniform -> broadcast
            f32x2 eg = av * bl2 + ml2;
            f32x2 e;
            e.x = __builtin_amdgcn_exp2f(eg.x);
            e.y = __builtin_amdgcn_exp2f(eg.y);
            den += e;
            num += e * av;
        }
        o1 = b1 + num / den;
    }
    __syncthreads();            // all waves done reading sa/sb

    // re-stage: sa <- o1 (for i-broadcast), sb <- rois_c
    *(f32x2*)&sa[lane][cp] = o1;
#pragma unroll
    for (int k = 0; k < 2; ++k) {
        int idx = t + 256 * k;
        sb[idx >> 3][idx & 7] = rc[k];
    }
    __syncthreads();

    // ---- stage 2: a = o1 (sa), b = rois_c (sb) ----
    {
        const f32x2 b2 = *(const f32x2*)&sb[lane][cp];
        float mx0 = o1.x, mn0 = o1.x, mx1 = o1.y, mn1 = o1.y;
#pragma unroll
        for (int s = 32; s; s >>= 1) {
            mx0 = fmaxf(mx0, __shfl_xor(mx0, s, 64));
            mn0 = fminf(mn0, __shfl_xor(mn0, s, 64));
            mx1 = fmaxf(mx1, __shfl_xor(mx1, s, 64));
            mn1 = fminf(mn1, __shfl_xor(mn1, s, 64));
        }
        f32x2 m;
        m.x = b2.x > 0.f ? b2.x * mx0 : b2.x * mn0;
        m.y = b2.y > 0.f ? b2.y * mx1 : b2.y * mn1;
        const f32x2 bl2 = b2 * L2E;
        const f32x2 ml2 = -m * L2E;
        f32x2 den = {0.f, 0.f}, num = {0.f, 0.f};
#pragma unroll 16
        for (int i = 0; i < 64; ++i) {
            const f32x2 av = *(const f32x2*)&sa[i][cp];   // uniform -> broadcast
            f32x2 eg = av * bl2 + ml2;
            f32x2 e;
            e.x = __builtin_amdgcn_exp2f(eg.x);
            e.y = __builtin_amdgcn_exp2f(eg.y);
            den += e;
            num += e * av;
        }
        *(f32x2*)&sc[lane][cp] = b2 + num / den;
    }
    __syncthreads();

#pragma unroll
    for (int k = 0; k < 2; ++k) {
        int idx = t + 256 * k;
        int i = idx >> 3, cc = idx & 7;
        out[(base + i) * 256 + cb + cc] = sc[i][cc];
    }
}

// ---------------------------------------------------------------------------
extern "C" void kernel_launch(void* const* d_in, const int* in_sizes, int n_in,
                              void* d_out, int out_size, void* d_ws, size_t ws_size,
                              hipStream_t stream) {
    // inputs: ori_feature_shape, rois_feature_a, feature_b, rois_feature_c, W_reg, b_reg
    const float* rois_a = (const float*)d_in[1];
    const float* feat   = (const float*)d_in[2];
    const float* rois_c = (const float*)d_in[3];
    const float* Wreg   = (const float*)d_in[4];
    const float* breg   = (const float*)d_in[5];
    float* out = (float*)d_out;
    float* partials = (float*)d_ws;                          // 512*288 fl = 589 KB
    float* rfb      = (float*)d_ws + (size_t)NPOS * PSTRIDE; // M*C fl = 4.7 MB

    kA<<<dim3(NPOS * 4), dim3(256), 0, stream>>>(feat, Wreg, partials);
    kB<<<dim3(NPOS * 2), dim3(256), 0, stream>>>(feat, partials, breg, rfb);
    kRf<<<dim3(NJOBS2), dim3(256), 0, stream>>>(rois_a, rfb, rois_c, out);
}

// Round 10
// 47.316 us; speedup vs baseline: 1.1281x; 1.1281x over previous
//
#include <hip/hip_runtime.h>

// N=8, C=256, H=W=64, A=9, bs=8, F=8, K=64, M=A*N*K=4608
constexpr int N_ = 8, C_ = 256, H_ = 64, W_ = 64, A_ = 9, F_ = 8, K_ = 64;
constexpr int NPOS = 512;                  // N*F*F positions
constexpr int PSTRIDE = 9 * 32;            // per-position partials: [9 anchors][32 slices]
constexpr int NJOBS = A_ * N_ * (C_ / 8);  // 2304 fused jobs (one (a,n), 8 ch each)
#define ALPHA_BS 0.8f                      // ALPHA(0.1) * bs(8)
#define L2E 1.442695040888963f

typedef float f32x2 __attribute__((ext_vector_type(2)));

// ---------------------------------------------------------------------------
// kA: conv partials, W register-stationary. 2048 blocks = (pair, g, chunk):
// chunk = bi&7 == XCD id; g = (n,gy); pair picks 2 of 8 gx. Thread t =
// (cl=t>>3, r=t&7) holds W[a][c][r][0..7] in regs (18 float4). Per gx:
// 2 feat float4 loads, 72 FMA, 6-step butterfly (8 rows + wave's 8 channels)
// -> one scalar per (wave, a, gx) -> partials[p][a][chunk*4+wid]. 589 KB.
// ---------------------------------------------------------------------------
__global__ __launch_bounds__(256) void kA(const float* __restrict__ feat,
                                          const float* __restrict__ Wreg,
                                          float* __restrict__ partials) {
    const int bi = blockIdx.x;
    const int chunk = bi & 7;
    const int g = (bi >> 3) & 63;
    const int pair = bi >> 9;              // 0..3
    const int n = g >> 3, gy = g & 7;
    const int t = threadIdx.x;
    const int lane = t & 63, wid = t >> 6;
    const int r = t & 7;
    const int c = chunk * 32 + (t >> 3);

    const float* wp = Wreg + chunk * 2048 + t * 8;
    float4 w0[9], w1[9];
#pragma unroll
    for (int a = 0; a < 9; ++a) {
        w0[a] = *(const float4*)(wp + (size_t)a * 16384);
        w1[a] = *(const float4*)(wp + (size_t)a * 16384 + 4);
    }
    const float* frow = feat + (((size_t)n * C_ + c) * H_ + gy * 8 + r) * W_;
#pragma unroll
    for (int i = 0; i < 2; ++i) {
        const int gx = pair * 2 + i;
        const float4 f0 = *(const float4*)(frow + gx * 8);
        const float4 f1 = *(const float4*)(frow + gx * 8 + 4);
        float* pp = partials + (size_t)(g * 8 + gx) * PSTRIDE + chunk * 4 + wid;
#pragma unroll
        for (int a = 0; a < 9; ++a) {
            float s = f0.x * w0[a].x + f0.y * w0[a].y + f0.z * w0[a].z + f0.w * w0[a].w;
            s = fmaf(f1.x, w1[a].x, s);
            s = fmaf(f1.y, w1[a].y, s);
            s = fmaf(f1.z, w1[a].z, s);
            s = fmaf(f1.w, w1[a].w, s);
            s += __shfl_xor(s, 1, 64);     // rows (lane bits 0..2)
            s += __shfl_xor(s, 2, 64);
            s += __shfl_xor(s, 4, 64);
            s += __shfl_xor(s, 8, 64);     // the wave's 8 channels (bits 3..5)
            s += __shfl_xor(s, 16, 64);
            s += __shfl_xor(s, 32, 64);
            if (lane == 0) pp[a * 32] = s;
        }
    }
}

// ---------------------------------------------------------------------------
// kRfB: offsets + bilinear sample + BOTH rois stages, one block per
// (a, n, 8-ch chunk). Block -> n = bi&7 (feat slice stays in that XCD's L2).
// Staging: (1) q=t&3,j=t>>2 threads reduce 32 partial slices (2 float4 +
// 2 shfl) -> tanh -> soff[j]; (2) sa <- rois_a, rc <- rois_c (coalesced);
// (3) after barrier, t=(j=t&63, cg=t>>6) samples 2 channels: offsets in
// +-0.8 => x0 in [2,60], x1=x0+1, y1=y0+1 — never clamped; 4 scalar loads
// + 4 FMA per channel -> sb[j][cc]. Then the two softmax stages exactly as
// before: wave w owns channel pair cp=2w, lane=j; a_i via uniform
// ds_read_b64 broadcast; f32x2 packed math; stage-2's a = stage-1's o1
// registers. kRf is trans-pipe-bound (151M v_exp_f32 ~ 31us floor) — the
// staging rides under it; rfb round-trip and kB dispatch eliminated.
// ---------------------------------------------------------------------------
__global__ __launch_bounds__(256, 4) void kRfB(const float* __restrict__ rois_a,
                                               const float* __restrict__ feat,
                                               const float* __restrict__ partials,
                                               const float* __restrict__ breg,
                                               const float* __restrict__ rois_c,
                                               float* __restrict__ out) {
    __shared__ __align__(16) float sa[64][10];
    __shared__ __align__(16) float sb[64][10];
    __shared__ __align__(16) float sc[64][10];
    __shared__ float soff[64];

    const int bi = blockIdx.x;
    const int n  = bi & 7;                 // XCD-aligned image
    const int r9 = bi >> 3;                // 0..287
    const int a9 = r9 >> 5;                // anchor 0..8
    const int cb = (r9 & 31) * 8;          // channel base
    const int na = a9 * N_ + n;
    const int t = threadIdx.x, lane = t & 63, w = t >> 6;
    const int cp = 2 * w;                  // this wave's channel pair
    const size_t base = (size_t)na * 64;

    // ---- offsets: thread (q=t&3, j=t>>2) reduces 8 of 32 slices ----
    {
        const int q = t & 3, jj = t >> 2;
        const float* pp = partials +
            (size_t)((n * 8 + (jj >> 3)) * 8 + (jj & 7)) * PSTRIDE + a9 * 32 + q * 8;
        const float4 v0 = *(const float4*)pp;
        const float4 v1 = *(const float4*)(pp + 4);
        float s = v0.x + v0.y + v0.z + v0.w + v1.x + v1.y + v1.z + v1.w;
        s += __shfl_xor(s, 1, 64);
        s += __shfl_xor(s, 2, 64);
        if (q == 0) soff[jj] = ALPHA_BS * tanhf(s + breg[a9]);
    }

    // ---- stage rois_a / prefetch rois_c (coalesced 32B segments) ----
    float rc[2];
#pragma unroll
    for (int k = 0; k < 2; ++k) {
        int idx = t + 256 * k;
        int i = idx >> 3, cc = idx & 7;
        sa[i][cc] = rois_a[(base + i) * 256 + cb + cc];
        rc[k]     = rois_c[(base + i) * 256 + cb + cc];
    }
    __syncthreads();

    // ---- bilinear sample -> sb: t = (j = t&63, cg = t>>6), 2 channels ----
    {
        const int j = t & 63, cg = t >> 6;
        const int gy = j >> 3, gx = j & 7;
        const float off = soff[j];
        const float cx = 3.5f + 8.0f * gx + off;
        const float cy = 3.5f + 8.0f * gy + off;
        const float x0f = floorf(cx), y0f = floorf(cy);
        const float wx = cx - x0f, wy = cy - y0f;
        const int x0 = (int)x0f, y0 = (int)y0f;    // in [2,60]: clamps never fire
        const float w00 = (1.f - wx) * (1.f - wy), w01 = wx * (1.f - wy);
        const float w10 = (1.f - wx) * wy,         w11 = wx * wy;
#pragma unroll
        for (int k = 0; k < 2; ++k) {
            const int c = cb + cg * 2 + k;
            const float* fp = feat + (((size_t)n * C_ + c) * H_ + y0) * W_ + x0;
            const float v00 = fp[0], v01 = fp[1];
            const float v10 = fp[W_], v11 = fp[W_ + 1];
            sb[j][cg * 2 + k] = w00 * v00 + w01 * v01 + w10 * v10 + w11 * v11;
        }
    }
    __syncthreads();

    // ---- stage 1: a = rois_a (sa), b = sampled (sb) ----
    const f32x2 a1 = *(const f32x2*)&sa[lane][cp];
    const f32x2 b1 = *(const f32x2*)&sb[lane][cp];
    f32x2 o1;
    {
        float mx0 = a1.x, mn0 = a1.x, mx1 = a1.y, mn1 = a1.y;
#pragma unroll
        for (int s = 32; s; s >>= 1) {
            mx0 = fmaxf(mx0, __shfl_xor(mx0, s, 64));
            mn0 = fminf(mn0, __shfl_xor(mn0, s, 64));
            mx1 = fmaxf(mx1, __shfl_xor(mx1, s, 64));
            mn1 = fminf(mn1, __shfl_xor(mn1, s, 64));
        }
        f32x2 m;
        m.x = b1.x > 0.f ? b1.x * mx0 : b1.x * mn0;
        m.y = b1.y > 0.f ? b1.y * mx1 : b1.y * mn1;
        const f32x2 bl2 = b1 * L2E;
        const f32x2 ml2 = -m * L2E;
        f32x2 den = {0.f, 0.f}, num = {0.f, 0.f};
#pragma unroll 8
        for (int i = 0; i < 64; ++i) {
            const f32x2 av = *(const f32x2*)&sa[i][cp];   // uniform -> broadcast
            f32x2 eg = av * bl2 + ml2;
            f32x2 e;
            e.x = __builtin_amdgcn_exp2f(eg.x);
            e.y = __builtin_amdgcn_exp2f(eg.y);
            den += e;
            num += e * av;
        }
        o1 = b1 + num / den;
    }
    __syncthreads();            // all waves done reading sa/sb

    // re-stage: sa <- o1 (for i-broadcast), sb <- rois_c
    *(f32x2*)&sa[lane][cp] = o1;
#pragma unroll
    for (int k = 0; k < 2; ++k) {
        int idx = t + 256 * k;
        sb[idx >> 3][idx & 7] = rc[k];
    }
    __syncthreads();

    // ---- stage 2: a = o1 (sa), b = rois_c (sb) ----
    {
        const f32x2 b2 = *(const f32x2*)&sb[lane][cp];
        float mx0 = o1.x, mn0 = o1.x, mx1 = o1.y, mn1 = o1.y;
#pragma unroll
        for (int s = 32; s; s >>= 1) {
            mx0 = fmaxf(mx0, __shfl_xor(mx0, s, 64));
            mn0 = fminf(mn0, __shfl_xor(mn0, s, 64));
            mx1 = fmaxf(mx1, __shfl_xor(mx1, s, 64));
            mn1 = fminf(mn1, __shfl_xor(mn1, s, 64));
        }
        f32x2 m;
        m.x = b2.x > 0.f ? b2.x * mx0 : b2.x * mn0;
        m.y = b2.y > 0.f ? b2.y * mx1 : b2.y * mn1;
        const f32x2 bl2 = b2 * L2E;
        const f32x2 ml2 = -m * L2E;
        f32x2 den = {0.f, 0.f}, num = {0.f, 0.f};
#pragma unroll 8
        for (int i = 0; i < 64; ++i) {
            const f32x2 av = *(const f32x2*)&sa[i][cp];   // uniform -> broadcast
            f32x2 eg = av * bl2 + ml2;
            f32x2 e;
            e.x = __builtin_amdgcn_exp2f(eg.x);
            e.y = __builtin_amdgcn_exp2f(eg.y);
            den += e;
            num += e * av;
        }
        *(f32x2*)&sc[lane][cp] = b2 + num / den;
    }
    __syncthreads();

    // ---- coalesced writeback ----
#pragma unroll
    for (int k = 0; k < 2; ++k) {
        int idx = t + 256 * k;
        int i = idx >> 3, cc = idx & 7;
        out[(base + i) * 256 + cb + cc] = sc[i][cc];
    }
}

// ---------------------------------------------------------------------------
extern "C" void kernel_launch(void* const* d_in, const int* in_sizes, int n_in,
                              void* d_out, int out_size, void* d_ws, size_t ws_size,
                              hipStream_t stream) {
    // inputs: ori_feature_shape, rois_feature_a, feature_b, rois_feature_c, W_reg, b_reg
    const float* rois_a = (const float*)d_in[1];
    const float* feat   = (const float*)d_in[2];
    const float* rois_c = (const float*)d_in[3];
    const float* Wreg   = (const float*)d_in[4];
    const float* breg   = (const float*)d_in[5];
    float* out = (float*)d_out;
    float* partials = (float*)d_ws;        // 512*288 floats = 589 KB

    kA<<<dim3(NPOS * 4), dim3(256), 0, stream>>>(feat, Wreg, partials);
    kRfB<<<dim3(NJOBS), dim3(256), 0, stream>>>(rois_a, feat, partials, breg,
                                                rois_c, out);
}